// Round 6
// baseline (417.447 us; speedup 1.0000x reference)
//
#include <hip/hip_runtime.h>

#define F     8192
#define KD    64      // coordinate dimensionality
#define NB    8       // neighbors
#define ROWS  64      // rows per knn block
#define JQ    4       // column quarters (2048 cols per block)
#define NROUND 64     // 64 rounds x (2 wc x 16 cols) = 2048 cols
#define CAP   96      // per-row candidate buffer capacity per fold interval
#define MKEEP 16      // per-row approx-candidate list length (superset of top-8)
#define MARGIN 0.25f  // >> 2x max |d_approx - d_exact| (~0.04)

typedef unsigned long long u64;
typedef unsigned short ushort_t;
typedef __attribute__((ext_vector_type(8))) short bf16x8;  // 8 bf16 = 4 VGPRs
typedef __attribute__((ext_vector_type(4))) float f32x4;

__device__ __forceinline__ u64 pack64(float d, int j) {
    // d >= 0 -> f32 bits order-preserving; u64 ascending == lex (d, j)
    return ((u64)__float_as_uint(d) << 32) | (unsigned)j;
}

__device__ __forceinline__ unsigned bf16rn(float x) {
    unsigned u = __float_as_uint(x);
    return (u + 0x7fffu + ((u >> 16) & 1u)) >> 16;
}

// ---------------------------------------------------------------------------
// Kernel 1: prep. sq (exact ascending-k fmaf chain, so dot(i,i)==sq[i] in the
// recheck => d(i,i)==0 exactly) + transposed bf16 hi/lo split of X:
// Xt[f*64+k]. hi = RN bf16(x); lo = RN bf16(x - hi) (Dekker split, exact
// residual). MFMA A/B fragments become contiguous 16B loads from Xt.
// ---------------------------------------------------------------------------
__global__ __launch_bounds__(256) void prep_kernel(const float* __restrict__ crd,
                                                   float* __restrict__ sq,
                                                   ushort_t* __restrict__ XtHi,
                                                   ushort_t* __restrict__ XtLo) {
    const int f = blockIdx.x * 256 + threadIdx.x;
    float acc = 0.f;
#pragma unroll
    for (int kb = 0; kb < 8; ++kb) {
        ushort_t hb[8], lb[8];
#pragma unroll
        for (int u = 0; u < 8; ++u) {
            int k = kb * 8 + u;
            float x = crd[k * F + f];
            acc = fmaf(x, x, acc);
            unsigned h = bf16rn(x);
            float hf = __uint_as_float(h << 16);
            float r = x - hf;                 // exact
            unsigned l = bf16rn(r);
            hb[u] = (ushort_t)h; lb[u] = (ushort_t)l;
        }
        *(uint4*)&XtHi[(size_t)f * KD + kb * 8] = *(const uint4*)hb;
        *(uint4*)&XtLo[(size_t)f * KD + kb * 8] = *(const uint4*)lb;
    }
    sq[f] = acc;
}

// ---------------------------------------------------------------------------
// Kernel 2: MFMA distance + approx top-16 per (row, col-quarter).
// Block = 512 thr = 8 waves = (wr 0..3: 16-row tile) x (wc 0..1: col stripe).
// grid = 128 row-blocks x 4 col-quarters = 512 -> 2 blocks/CU (LDS 57KB).
// Per 16x16 tile: 6 MFMAs (hihi K=64 in za; hilo+lohi in zb), B fragments
// = 4x16B contiguous global loads (L2-resident, software-prefetched one
// round ahead). d_approx = sq[i]+sq[j]-2(za+zb); |err| <= ~0.04.
// Selection: accept d <= (running approx d8 + MARGIN) -> LDS buffer ->
// periodic fold into sorted top-16 list (u64 lex). Folds at rounds
// 0,1,2,3,7,15,31,63 keep E[appends/interval] ~8 << CAP=96.
// MFMA layouts (HW-verified, guide §3): A[m=lane&15][k=quad*8+j],
// B[k=quad*8+j][n=lane&15], C/D col=lane&15, row=quad*4+reg.
// ---------------------------------------------------------------------------
__global__ __launch_bounds__(512, 4) void knn_mfma(const ushort_t* __restrict__ XtHi,
                                                   const ushort_t* __restrict__ XtLo,
                                                   const float* __restrict__ sq,
                                                   u64* __restrict__ part) {
    __shared__ u64 buf[ROWS][CAP + 1];     // 49.7 KB
    __shared__ u64 lst[ROWS][MKEEP];       // 8 KB, sorted ascending
    __shared__ __align__(16) float thr[ROWS];
    __shared__ int cnt[ROWS];

    const int tid  = threadIdx.x;
    const int wave = tid >> 6;
    const int tx   = tid & 63;
    const int wr   = wave >> 1;            // 0..3: row tile
    const int wc   = wave & 1;             // 0..1: col stripe
    const int quad = tx >> 4;
    const int n    = tx & 15;
    const int blockRow = (blockIdx.x >> 2) * ROWS;
    const int jq   = blockIdx.x & 3;
    const int jbase = jq * (F / JQ);
    const int i0   = blockRow + wr * 16;

    if (tid < ROWS) { cnt[tid] = 0; thr[tid] = __int_as_float(0x7f800000); }
#pragma unroll
    for (int e = tid; e < ROWS * MKEEP; e += 512) lst[e >> 4][e & 15] = ~0ULL;
    __syncthreads();

    // A fragments: held in registers across the whole sweep
    const size_t abase = (size_t)(i0 + n) * KD + quad * 8;
    const bf16x8 ah0 = *(const bf16x8*)(XtHi + abase);
    const bf16x8 ah1 = *(const bf16x8*)(XtHi + abase + 32);
    const bf16x8 al0 = *(const bf16x8*)(XtLo + abase);
    const bf16x8 al1 = *(const bf16x8*)(XtLo + abase + 32);
    const f32x4 sqi = *(const f32x4*)&sq[i0 + quad * 4];
    f32x4 tdv = {__int_as_float(0x7f800000), __int_as_float(0x7f800000),
                 __int_as_float(0x7f800000), __int_as_float(0x7f800000)};

    // prefetch round 0 B fragments
    int j0 = jbase + wc * 16;
    size_t bb = (size_t)(j0 + n) * KD + quad * 8;
    bf16x8 bh0 = *(const bf16x8*)(XtHi + bb), bh1 = *(const bf16x8*)(XtHi + bb + 32);
    bf16x8 bl0 = *(const bf16x8*)(XtLo + bb), bl1 = *(const bf16x8*)(XtLo + bb + 32);
    float sqj = sq[j0 + n];

    for (int round = 0; round < NROUND; ++round) {
        const bf16x8 ch0 = bh0, ch1 = bh1, cl0 = bl0, cl1 = bl1;
        const float csqj = sqj;
        const int   cj   = j0 + n;
        if (round + 1 < NROUND) {          // software prefetch next round
            j0 += 32;
            size_t nb = (size_t)(j0 + n) * KD + quad * 8;
            bh0 = *(const bf16x8*)(XtHi + nb); bh1 = *(const bf16x8*)(XtHi + nb + 32);
            bl0 = *(const bf16x8*)(XtLo + nb); bl1 = *(const bf16x8*)(XtLo + nb + 32);
            sqj = sq[j0 + n];
        }

        f32x4 za = {0.f, 0.f, 0.f, 0.f};   // hi*hi
        f32x4 zb = {0.f, 0.f, 0.f, 0.f};   // hi*lo + lo*hi
        za = __builtin_amdgcn_mfma_f32_16x16x32_bf16(ah0, ch0, za, 0, 0, 0);
        za = __builtin_amdgcn_mfma_f32_16x16x32_bf16(ah1, ch1, za, 0, 0, 0);
        zb = __builtin_amdgcn_mfma_f32_16x16x32_bf16(ah0, cl0, zb, 0, 0, 0);
        zb = __builtin_amdgcn_mfma_f32_16x16x32_bf16(ah1, cl1, zb, 0, 0, 0);
        zb = __builtin_amdgcn_mfma_f32_16x16x32_bf16(al0, ch0, zb, 0, 0, 0);
        zb = __builtin_amdgcn_mfma_f32_16x16x32_bf16(al1, ch1, zb, 0, 0, 0);

#pragma unroll
        for (int r = 0; r < 4; ++r) {
            float dot = za[r] + zb[r];
            float d = fmaxf((sqi[r] + csqj) - 2.f * dot, 0.f);
            if (d <= tdv[r]) {             // tdv = approx-d8 + MARGIN
                int row = wr * 16 + quad * 4 + r;
                int q = atomicAdd(&cnt[row], 1);
                if (q < CAP) buf[row][q] = pack64(d, cj);
            }
        }

        if ((0x800000008000808FULL >> round) & 1ULL) {   // rounds 0,1,2,3,7,15,31,63
            __syncthreads();
            if (tid < ROWS) {
                u64 L[MKEEP];
#pragma unroll
                for (int s = 0; s < MKEEP; ++s) L[s] = lst[tid][s];
                int nn = min(cnt[tid], CAP);
                for (int ii = 0; ii < nn; ++ii) {
                    u64 x = buf[tid][ii];
                    if (x < L[MKEEP - 1]) {
                        L[MKEEP - 1] = x;
#pragma unroll
                        for (int q = MKEEP - 1; q > 0; --q)
                            if (L[q] < L[q - 1]) { u64 w = L[q]; L[q] = L[q - 1]; L[q - 1] = w; }
                    }
                }
#pragma unroll
                for (int s = 0; s < MKEEP; ++s) lst[tid][s] = L[s];
                thr[tid] = __uint_as_float((unsigned)(L[NB - 1] >> 32)) + MARGIN;
                cnt[tid] = 0;
            }
            __syncthreads();
            tdv = *(const f32x4*)&thr[wr * 16 + quad * 4];
        }
    }

    // write the per-quarter top-16 list (final fold happened at round 63)
#pragma unroll
    for (int e = tid; e < ROWS * MKEEP; e += 512) {
        int rr = e >> 4, ss = e & 15;
        part[((size_t)jq * F + blockRow + rr) * MKEEP + ss] = lst[rr][ss];
    }
}

// ---------------------------------------------------------------------------
// Kernel 3: exact recheck. For each row: 4 quarters x 16 candidates = 64.
// Recompute d exactly (ascending-k fmaf fp32 chain, same as sq => d(i,i)=0
// exactly), select true top-8 by u64 (d,j) lex = exact jax tie-break.
// ---------------------------------------------------------------------------
__global__ __launch_bounds__(256) void recheck_kernel(const float* __restrict__ crd,
                                                      const float* __restrict__ sq,
                                                      const u64* __restrict__ part,
                                                      int* __restrict__ knn) {
    __shared__ u64 cand[4][65];
    const int tid = threadIdx.x;
    const int rl = tid >> 6, c = tid & 63;
    const int i = blockIdx.x * 4 + rl;
    u64 pc = part[((size_t)(c >> 4) * F + i) * MKEEP + (c & 15)];
    int j = (int)(pc & 0xffffffffu);
    float acc = 0.f;
    for (int k = 0; k < KD; ++k)
        acc = fmaf(crd[k * F + i], crd[k * F + j], acc);
    float d = fmaxf((sq[i] + sq[j]) - 2.f * acc, 0.f);
    cand[rl][c] = pack64(d, j);
    __syncthreads();
    if (tid < 4) {
        u64 C[64];
#pragma unroll
        for (int q = 0; q < 64; ++q) C[q] = cand[tid][q];
#pragma unroll
        for (int s = 0; s < NB; ++s) {
            int bp = 0; u64 bv = C[0];
            for (int q = 1; q < 64; ++q)
                if (C[q] < bv) { bv = C[q]; bp = q; }
            C[bp] = ~0ULL;
            knn[(blockIdx.x * 4 + tid) * NB + s] = (int)(bv & 0xffffffffu);
        }
    }
}

// ---------------------------------------------------------------------------
// Kernel 4: gather. 4 blocks per (b,c) row (R5's 1 block/CU was latency-
// bound at ~65us). Row staged in LDS; int4 knn + float4 stores coalesced.
// ---------------------------------------------------------------------------
__global__ __launch_bounds__(512) void gather_kernel(const float* __restrict__ inp,
                                                     const int* __restrict__ knn,
                                                     float* __restrict__ out) {
    __shared__ float row[F];    // 32 KB
    const int bc    = blockIdx.x >> 2;
    const int chunk = blockIdx.x & 3;
    const int tid   = threadIdx.x;

    const float4* in4  = (const float4*)(inp + (size_t)bc * F);
    float4*       row4 = (float4*)row;
#pragma unroll
    for (int i = 0; i < (F / 4) / 512; ++i) row4[i * 512 + tid] = in4[i * 512 + tid];
    __syncthreads();

    const int4* kn4 = (const int4*)knn;
    float4*     ou4 = (float4*)(out + (size_t)bc * (F * NB));

#pragma unroll
    for (int i = 0; i < 8; ++i) {              // 16384/chunk / 4 / 512
        int e = chunk * 4096 + i * 512 + tid;
        int4 idx = kn4[e];
        if (e == 0) idx.x = 0;                 // flat_idx[0] hardcoded 0
        float4 o;
        o.x = row[idx.x]; o.y = row[idx.y]; o.z = row[idx.z]; o.w = row[idx.w];
        ou4[e] = o;
    }
}

extern "C" void kernel_launch(void* const* d_in, const int* in_sizes, int n_in,
                              void* d_out, int out_size, void* d_ws, size_t ws_size,
                              hipStream_t stream) {
    const float* inp = (const float*)d_in[0];   // (64,4,8192,1) fp32
    const float* crd = (const float*)d_in[1];   // (64,1,8192)  fp32
    float* out = (float*)d_out;                 // (64,4,65536,1) fp32

    ushort_t* XtHi = (ushort_t*)d_ws;                             // 1 MB
    ushort_t* XtLo = (ushort_t*)((char*)d_ws + (1u << 20));       // 1 MB
    float*    sq   = (float*)((char*)d_ws + (2u << 20));          // 32 KB
    int*      knn  = (int*)((char*)d_ws + (2u << 20) + (1u << 15));// 256 KB
    u64*      part = (u64*)((char*)d_ws + (3u << 20));            // 4 MB

    prep_kernel<<<F / 256, 256, 0, stream>>>(crd, sq, XtHi, XtLo);
    knn_mfma<<<(F / ROWS) * JQ, 512, 0, stream>>>(XtHi, XtLo, sq, part);
    recheck_kernel<<<F / 4, 256, 0, stream>>>(crd, sq, part, knn);
    gather_kernel<<<256 * 4, 512, 0, stream>>>(inp, knn, out);
}

// Round 7
// 356.059 us; speedup vs baseline: 1.1724x; 1.1724x over previous
//
#include <hip/hip_runtime.h>

#define F      8192
#define KD     64     // coordinate dimensionality
#define NB     8      // neighbors
#define WROWS  32     // rows per block (all 8 waves share these rows)
#define MKEEP  16     // per-(row,quarter) approx list length (superset of top-8)
#define JQ     4      // column quarters
#define CPR    128    // cols per block-round (8 waves x 16)
#define NROUND ((F / JQ) / CPR)   // 16
#define CAP    160    // >= 128 worst-case appends in round 0 (thr = +inf)
#define MARGIN 0.25f  // >> 2x max |d_approx - d_exact| (~0.04)

typedef unsigned long long u64;
typedef unsigned short ushort_t;
typedef __attribute__((ext_vector_type(8))) short bf16x8;  // 8 bf16 = 4 VGPRs
typedef __attribute__((ext_vector_type(4))) float f32x4;

__device__ __forceinline__ u64 pack64(float d, int j) {
    // d >= 0 -> f32 bits order-preserving; u64 ascending == lex (d, j)
    return ((u64)__float_as_uint(d) << 32) | (unsigned)j;
}

__device__ __forceinline__ unsigned bf16rn(float x) {
    unsigned u = __float_as_uint(x);
    return (u + 0x7fffu + ((u >> 16) & 1u)) >> 16;
}

// ---------------------------------------------------------------------------
// Kernel 1: prep. sq (exact ascending-k fmaf chain — recheck uses the same
// chain so dot(i,i)==sq[i] bit-exact => d(i,i)==0), transposed bf16 hi/lo
// split (MFMA fragments = contiguous 16B), and transposed fp32 Xt32 (recheck
// reads contiguous 256B rows instead of R6's 32KB-strided column gather).
// ---------------------------------------------------------------------------
__global__ __launch_bounds__(256) void prep_kernel(const float* __restrict__ crd,
                                                   float* __restrict__ sq,
                                                   ushort_t* __restrict__ XtHi,
                                                   ushort_t* __restrict__ XtLo,
                                                   float* __restrict__ Xt32) {
    const int f = blockIdx.x * 256 + threadIdx.x;
    float acc = 0.f;
#pragma unroll
    for (int kb = 0; kb < 8; ++kb) {
        ushort_t hb[8], lb[8];
        float    xv[8];
#pragma unroll
        for (int u = 0; u < 8; ++u) {
            int k = kb * 8 + u;
            float x = crd[k * F + f];
            acc = fmaf(x, x, acc);
            unsigned h = bf16rn(x);
            float hf = __uint_as_float(h << 16);
            unsigned l = bf16rn(x - hf);       // Dekker split, exact residual
            hb[u] = (ushort_t)h; lb[u] = (ushort_t)l; xv[u] = x;
        }
        *(uint4*)&XtHi[(size_t)f * KD + kb * 8] = *(const uint4*)hb;
        *(uint4*)&XtLo[(size_t)f * KD + kb * 8] = *(const uint4*)lb;
        *(float4*)&Xt32[(size_t)f * KD + kb * 8]     = *(const float4*)&xv[0];
        *(float4*)&Xt32[(size_t)f * KD + kb * 8 + 4] = *(const float4*)&xv[4];
    }
    sq[f] = acc;
}

// ---------------------------------------------------------------------------
// Kernel 2: MFMA distance + approx top-16 per (row, col-quarter).
// Block = 512 thr = 8 waves; ALL waves share the block's 32 rows (A frags in
// registers, 2 16-row tiles); each wave owns a distinct 16-col stripe per
// round -> zero intra-block B redundancy, 12 MFMAs per 4KB B (2x R6 reuse).
// Unroll-2 double-buffered B prefetch (2-round depth covers L2 latency).
// Accept test transformed: d<=thr  <=>  dot >= 0.5*(sqi-thr) + 0.5*sqj
// (3 VALU/cand; exact d only in rare taken branch; MARGIN covers rounding).
// Folds (1 thread/row) at rounds 0,1,3,7,15 -> CAP 160 never overflows
// (round 0 worst case = 128 appends/row).
// MFMA layouts (HW-verified): A[m=lane&15][k=quad*8+j], C/D col=lane&15,
// row=quad*4+reg.
// ---------------------------------------------------------------------------
__global__ __launch_bounds__(512, 4) void knn_mfma(const ushort_t* __restrict__ XtHi,
                                                   const ushort_t* __restrict__ XtLo,
                                                   const float* __restrict__ sq,
                                                   u64* __restrict__ part) {
    __shared__ u64 buf[WROWS][CAP + 1];   // 41.2 KB
    __shared__ u64 lst[WROWS][MKEEP];     // 4 KB
    __shared__ __align__(16) float thr[WROWS];
    __shared__ int cnt[WROWS];

    const int tid  = threadIdx.x;
    const int wave = tid >> 6;
    const int tx   = tid & 63;
    const int quad = tx >> 4;
    const int n    = tx & 15;
    const int blockRow = (blockIdx.x >> 2) * WROWS;
    const int jq    = blockIdx.x & 3;
    const int jbase = jq * (F / JQ);

    if (tid < WROWS) { cnt[tid] = 0; thr[tid] = __int_as_float(0x7f800000); }
#pragma unroll
    for (int e = tid; e < WROWS * MKEEP; e += 512) lst[e >> 4][e & 15] = ~0ULL;
    __syncthreads();

    // A fragments for both 16-row tiles, resident all sweep (32 VGPRs)
    const size_t a0 = (size_t)(blockRow + n) * KD + quad * 8;
    const size_t a1 = (size_t)(blockRow + 16 + n) * KD + quad * 8;
    const bf16x8 a0h0 = *(const bf16x8*)(XtHi + a0), a0h1 = *(const bf16x8*)(XtHi + a0 + 32);
    const bf16x8 a0l0 = *(const bf16x8*)(XtLo + a0), a0l1 = *(const bf16x8*)(XtLo + a0 + 32);
    const bf16x8 a1h0 = *(const bf16x8*)(XtHi + a1), a1h1 = *(const bf16x8*)(XtHi + a1 + 32);
    const bf16x8 a1l0 = *(const bf16x8*)(XtLo + a1), a1l1 = *(const bf16x8*)(XtLo + a1 + 32);
    const f32x4 sqi0 = *(const f32x4*)&sq[blockRow + quad * 4];
    const f32x4 sqi1 = *(const f32x4*)&sq[blockRow + 16 + quad * 4];
    f32x4 pre0, pre1;  // 0.5*(sqi - thr); thr=+inf -> -inf -> accept all
#pragma unroll
    for (int r = 0; r < 4; ++r) { pre0[r] = -__int_as_float(0x7f800000);
                                  pre1[r] = -__int_as_float(0x7f800000); }

    const int laneCol = wave * 16 + n;    // col offset within a round's 128

#define LOADB(H0, H1, L0, L1, SJ, RND)                                        \
    {   int jc = jbase + (RND) * CPR + laneCol;                               \
        size_t bo = (size_t)jc * KD + quad * 8;                               \
        H0 = *(const bf16x8*)(XtHi + bo); H1 = *(const bf16x8*)(XtHi + bo + 32); \
        L0 = *(const bf16x8*)(XtLo + bo); L1 = *(const bf16x8*)(XtLo + bo + 32); \
        SJ = sq[jc]; }

#define PROCESS(H0, H1, L0, L1, SJ, RND)                                      \
    {   f32x4 za0 = {0,0,0,0}, zb0 = {0,0,0,0}, za1 = {0,0,0,0}, zb1 = {0,0,0,0}; \
        za0 = __builtin_amdgcn_mfma_f32_16x16x32_bf16(a0h0, H0, za0, 0, 0, 0); \
        za0 = __builtin_amdgcn_mfma_f32_16x16x32_bf16(a0h1, H1, za0, 0, 0, 0); \
        zb0 = __builtin_amdgcn_mfma_f32_16x16x32_bf16(a0h0, L0, zb0, 0, 0, 0); \
        zb0 = __builtin_amdgcn_mfma_f32_16x16x32_bf16(a0h1, L1, zb0, 0, 0, 0); \
        zb0 = __builtin_amdgcn_mfma_f32_16x16x32_bf16(a0l0, H0, zb0, 0, 0, 0); \
        zb0 = __builtin_amdgcn_mfma_f32_16x16x32_bf16(a0l1, H1, zb0, 0, 0, 0); \
        za1 = __builtin_amdgcn_mfma_f32_16x16x32_bf16(a1h0, H0, za1, 0, 0, 0); \
        za1 = __builtin_amdgcn_mfma_f32_16x16x32_bf16(a1h1, H1, za1, 0, 0, 0); \
        zb1 = __builtin_amdgcn_mfma_f32_16x16x32_bf16(a1h0, L0, zb1, 0, 0, 0); \
        zb1 = __builtin_amdgcn_mfma_f32_16x16x32_bf16(a1h1, L1, zb1, 0, 0, 0); \
        zb1 = __builtin_amdgcn_mfma_f32_16x16x32_bf16(a1l0, H0, zb1, 0, 0, 0); \
        zb1 = __builtin_amdgcn_mfma_f32_16x16x32_bf16(a1l1, H1, zb1, 0, 0, 0); \
        const int jc = jbase + (RND) * CPR + laneCol;                         \
        const float h = 0.5f * SJ;                                            \
        _Pragma("unroll")                                                     \
        for (int r = 0; r < 4; ++r) {                                         \
            float dot = za0[r] + zb0[r];                                      \
            if (dot >= pre0[r] + h) {                                         \
                float d = fmaxf((sqi0[r] + SJ) - 2.f * dot, 0.f);             \
                int row = quad * 4 + r;                                       \
                int q = atomicAdd(&cnt[row], 1);                              \
                if (q < CAP) buf[row][q] = pack64(d, jc);                     \
            }                                                                 \
            dot = za1[r] + zb1[r];                                            \
            if (dot >= pre1[r] + h) {                                         \
                float d = fmaxf((sqi1[r] + SJ) - 2.f * dot, 0.f);             \
                int row = 16 + quad * 4 + r;                                  \
                int q = atomicAdd(&cnt[row], 1);                              \
                if (q < CAP) buf[row][q] = pack64(d, jc);                     \
            }                                                                 \
        } }

#define FOLD()                                                                \
    {   __syncthreads();                                                      \
        if (tid < WROWS) {                                                    \
            u64 L[MKEEP];                                                     \
            _Pragma("unroll")                                                 \
            for (int s = 0; s < MKEEP; ++s) L[s] = lst[tid][s];               \
            int nn = min(cnt[tid], CAP);                                      \
            for (int ii = 0; ii < nn; ++ii) {                                 \
                u64 x = buf[tid][ii];                                         \
                if (x < L[MKEEP - 1]) {                                       \
                    L[MKEEP - 1] = x;                                         \
                    _Pragma("unroll")                                         \
                    for (int q = MKEEP - 1; q > 0; --q)                       \
                        if (L[q] < L[q - 1]) { u64 w = L[q]; L[q] = L[q - 1]; L[q - 1] = w; } \
                }                                                             \
            }                                                                 \
            _Pragma("unroll")                                                 \
            for (int s = 0; s < MKEEP; ++s) lst[tid][s] = L[s];               \
            thr[tid] = __uint_as_float((unsigned)(L[NB - 1] >> 32)) + MARGIN; \
            cnt[tid] = 0;                                                     \
        }                                                                     \
        __syncthreads();                                                      \
        {   f32x4 t0 = *(const f32x4*)&thr[quad * 4];                         \
            f32x4 t1 = *(const f32x4*)&thr[16 + quad * 4];                    \
            _Pragma("unroll")                                                 \
            for (int r = 0; r < 4; ++r) {                                     \
                pre0[r] = 0.5f * (sqi0[r] - t0[r]);                           \
                pre1[r] = 0.5f * (sqi1[r] - t1[r]);                           \
            } } }

    bf16x8 B0h0, B0h1, B0l0, B0l1, B1h0, B1h1, B1l0, B1l1;
    float  B0sj, B1sj;
    LOADB(B0h0, B0h1, B0l0, B0l1, B0sj, 0)
    LOADB(B1h0, B1h1, B1l0, B1l1, B1sj, 1)

    for (int rr = 0; rr < NROUND; rr += 2) {
        PROCESS(B0h0, B0h1, B0l0, B0l1, B0sj, rr)
        if (rr + 2 < NROUND) LOADB(B0h0, B0h1, B0l0, B0l1, B0sj, rr + 2)
        if (rr == 0) FOLD()
        PROCESS(B1h0, B1h1, B1l0, B1l1, B1sj, rr + 1)
        if (rr + 3 < NROUND) LOADB(B1h0, B1h1, B1l0, B1l1, B1sj, rr + 3)
        if (((rr + 1) & (rr + 2)) == 0) FOLD()   // rounds 1,3,7,15
    }

    // write per-quarter top-16 lists (final fold happened at round 15)
#pragma unroll
    for (int e = tid; e < WROWS * MKEEP; e += 512) {
        int rrw = e >> 4, ss = e & 15;
        part[((size_t)jq * F + blockRow + rrw) * MKEEP + ss] = lst[rrw][ss];
    }
#undef LOADB
#undef PROCESS
#undef FOLD
}

// ---------------------------------------------------------------------------
// Kernel 3: exact recheck. Block = 4 rows x 64 candidates (4 waves, one row
// per wave). B rows read CONTIGUOUSLY from Xt32 (256B/candidate, L2-hot);
// A row staged in LDS (broadcast reads). Exact ascending-k fmaf chain (bit-
// identical to sq's => d(i,i)==0). Top-8 via in-register wave shuffle-pop on
// packed u64 -> exact jax (d, j) tie-break.
// ---------------------------------------------------------------------------
__global__ __launch_bounds__(256) void recheck_kernel(const float* __restrict__ Xt32,
                                                      const float* __restrict__ sq,
                                                      const u64* __restrict__ part,
                                                      int* __restrict__ knn) {
    __shared__ float A_s[4][KD];
    const int tid = threadIdx.x;
    const int rl = tid >> 6, tx = tid & 63;
    const int i = blockIdx.x * 4 + rl;

    A_s[tid >> 6][tid & 63] = Xt32[(size_t)(blockIdx.x * 4 + (tid >> 6)) * KD + (tid & 63)];
    __syncthreads();

    u64 pc = part[((size_t)(tx >> 4) * F + i) * MKEEP + (tx & 15)];
    int j = (int)(pc & 0xffffffffu);

    const float4* b4 = (const float4*)(Xt32 + (size_t)j * KD);
    float acc = 0.f;
#pragma unroll
    for (int kk = 0; kk < KD / 4; ++kk) {
        float4 b = b4[kk];
        const float* a = &A_s[rl][kk * 4];
        acc = fmaf(a[0], b.x, acc);
        acc = fmaf(a[1], b.y, acc);
        acc = fmaf(a[2], b.z, acc);
        acc = fmaf(a[3], b.w, acc);
    }
    float d = fmaxf((sq[i] + sq[j]) - 2.f * acc, 0.f);
    u64 mine = pack64(d, j);

    int myout = 0;
#pragma unroll
    for (int s = 0; s < NB; ++s) {
        u64 m = mine;
#pragma unroll
        for (int off = 32; off >= 1; off >>= 1) {
            u64 o = __shfl_xor(m, off, 64);
            if (o < m) m = o;
        }
        if (mine == m) mine = ~0ULL;       // pop (unique (d,j) per row)
        if (tx == s) myout = (int)(m & 0xffffffffu);
    }
    if (tx < NB) knn[(size_t)i * NB + tx] = myout;
}

// ---------------------------------------------------------------------------
// Kernel 4: gather. 4 blocks per (b,c); row staged in LDS; int4 knn +
// float4 stores, coalesced.
// ---------------------------------------------------------------------------
__global__ __launch_bounds__(512) void gather_kernel(const float* __restrict__ inp,
                                                     const int* __restrict__ knn,
                                                     float* __restrict__ out) {
    __shared__ float row[F];    // 32 KB
    const int bc    = blockIdx.x >> 2;
    const int chunk = blockIdx.x & 3;
    const int tid   = threadIdx.x;

    const float4* in4  = (const float4*)(inp + (size_t)bc * F);
    float4*       row4 = (float4*)row;
#pragma unroll
    for (int i = 0; i < (F / 4) / 512; ++i) row4[i * 512 + tid] = in4[i * 512 + tid];
    __syncthreads();

    const int4* kn4 = (const int4*)knn;
    float4*     ou4 = (float4*)(out + (size_t)bc * (F * NB));

#pragma unroll
    for (int i = 0; i < 8; ++i) {
        int e = chunk * 4096 + i * 512 + tid;
        int4 idx = kn4[e];
        if (e == 0) idx.x = 0;             // flat_idx[0] hardcoded 0
        float4 o;
        o.x = row[idx.x]; o.y = row[idx.y]; o.z = row[idx.z]; o.w = row[idx.w];
        ou4[e] = o;
    }
}

extern "C" void kernel_launch(void* const* d_in, const int* in_sizes, int n_in,
                              void* d_out, int out_size, void* d_ws, size_t ws_size,
                              hipStream_t stream) {
    const float* inp = (const float*)d_in[0];   // (64,4,8192,1) fp32
    const float* crd = (const float*)d_in[1];   // (64,1,8192)  fp32
    float* out = (float*)d_out;                 // (64,4,65536,1) fp32

    ushort_t* XtHi = (ushort_t*)d_ws;                               // 1 MB
    ushort_t* XtLo = (ushort_t*)((char*)d_ws + (1u << 20));         // 1 MB
    float*    Xt32 = (float*)((char*)d_ws + (2u << 20));            // 2 MB
    float*    sq   = (float*)((char*)d_ws + (4u << 20));            // 32 KB
    int*      knn  = (int*)((char*)d_ws + (4u << 20) + (1u << 15)); // 256 KB
    u64*      part = (u64*)((char*)d_ws + (5u << 20));              // 4 MB

    prep_kernel<<<F / 256, 256, 0, stream>>>(crd, sq, XtHi, XtLo, Xt32);
    knn_mfma<<<(F / WROWS) * JQ, 512, 0, stream>>>(XtHi, XtLo, sq, part);
    recheck_kernel<<<F / 4, 256, 0, stream>>>(Xt32, sq, part, knn);
    gather_kernel<<<256 * 4, 512, 0, stream>>>(inp, knn, out);
}